// Round 10
// baseline (18181.047 us; speedup 1.0000x reference)
//
#include <hip/hip_runtime.h>
#include <hip/hip_bf16.h>

#define DEV static __device__ __forceinline__

constexpr int Tn = 1024;
constexpr float LOG2E = 1.4426950408889634f;

// ---- g_ws float offsets ----
constexpr int OFF_H     = 0;        // 384*384
constexpr int OFF_E     = 147456;   // 16384
constexpr int OFF_EINV  = 163840;   // 16384
constexpr int OFF_M     = 180224;   // 1024
constexpr int OFF_MINV  = 181248;   // 1024
constexpr int OFF_GL2   = 182272;   // 128: (2/lam)*log2e
constexpr int OFF_FH    = 182400;   // 16384  Fh = Einv H31
constexpr int OFF_B1H   = 198784;   // 16384  B1h = Einv H32
constexpr int OFF_B2H   = 215168;   // 4096   B2h = Einv B2
constexpr int OFF_W0    = 219264;   // 4096   W0 = Minv C2
constexpr int OFF_WC    = 223360;   // 4096
constexpr int OFF_CF    = 227456;   // 16384  CF = C1 Fh
constexpr int OFF_CB    = 243840;   // 16384  CB = C1 B1h
constexpr int OFF_CB2   = 260224;   // 4096   CB2 = C1 B2h
constexpr int OFF_PF    = 264320;   // 16384 (8192 f2) PF[j][l]=(Fh[l][j],Fh[l+64][j])
constexpr int OFF_PB    = 280704;   // 16384 B1h pairs
constexpr int OFF_PCF   = 297088;   // 16384 gl2-scaled CF pairs
constexpr int OFF_PCB   = 313472;   // 16384 gl2-scaled CB pairs
constexpr int OFF_SAB   = 329856;   // 8192  (4096 f2) scan couplings lower
constexpr int OFF_SB2   = 338048;   // 4096            scan couplings upper
constexpr int OFF_BUQ   = 342144;   // 4096 (2048 f2)
constexpr int OFF_D12Q  = 346240;   // 4096 gl2-scaled D12 pairs
constexpr int OFF_SCB2  = 350336;   // 4096 gl2-scaled CB2 pairs
constexpr int OFF_WCS   = 354432;   // 4096
constexpr int OFF_C2Y   = 358528;   // 4096  C2Y[m][o] = C2[o][m]
constexpr int OFF_D21Y  = 362624;   // 4096
constexpr int OFF_D22Y  = 366720;   // 1024
constexpr int OFF_AUG   = 367744;   // 32768
constexpr int OFF_AUG2  = 400512;   // 2048
constexpr int OFF_X0    = 402560;   // 32768
constexpr int OFF_A0    = 435328;   // 32768
constexpr int WS_FLOATS = 468096;

__device__ __align__(16) float g_ws[WS_FLOATS];
__device__ int g_isf32;

DEV float ld(const void* p, size_t i, int f) {
  return f ? ((const float*)p)[i]
           : __bfloat162float(((const __hip_bfloat16*)p)[i]);
}
DEV float rdlane(float v, int l) {
  return __int_as_float(__builtin_amdgcn_readlane(__float_as_int(v), l));
}

// ---------------- Prep 0: detect input dtype ----------------
__global__ void k_detect(const void* __restrict__ X) {
  if (threadIdx.x == 0) {
    const __hip_bfloat16* p = (const __hip_bfloat16*)X;
    int bad = 0;
    for (int i = 0; i < 512; ++i) {
      float v = __bfloat162float(p[i]);
      if (!(v > -1e6f && v < 1e6f)) bad++;
    }
    g_isf32 = (bad > 0) ? 1 : 0;
  }
}

// ---------------- Prep 1: H = X^T X + eps I ----------------
__global__ void k_H(const void* __restrict__ X) {
  const int f = g_isf32;
  float* ws = g_ws;
  int id = blockIdx.x * 256 + threadIdx.x;   // 147456
  int r = id / 384, c = id % 384;
  float acc = 0.f;
  for (int k = 0; k < 384; ++k)
    acc = fmaf(ld(X, k * 384 + r, f), ld(X, k * 384 + c, f), acc);
  if (r == c) acc += 0.001f;
  ws[OFF_H + id] = acc;
}

// ---------------- Prep 2: E, gl2, M ----------------
__global__ void k_derived(const void* __restrict__ Y, const void* __restrict__ C2) {
  const int f = g_isf32;
  float* ws = g_ws;
  const float* H = ws + OFF_H;
  int id = blockIdx.x * 256 + threadIdx.x;
  if (id < 16384) {
    int i = id >> 7, j = id & 127;
    ws[OFF_E + id] = 0.5f * (H[i * 384 + j] + H[(256 + i) * 384 + 256 + j]
                             + ld(Y, i * 128 + j, f) - ld(Y, j * 128 + i, f));
  } else if (id < 16512) {
    int i = id - 16384;
    ws[OFF_GL2 + i] = LOG2E * 4.f / H[(128 + i) * 384 + 128 + i];
  } else if (id < 17536) {
    int t = id - 16512; int a = t >> 5, b = t & 31;
    float acc = 0.f;
    for (int j = 0; j < 128; ++j)
      acc = fmaf(ld(C2, a * 128 + j, f), ld(C2, b * 128 + j, f), acc);
    ws[OFF_M + t] = acc;
  }
}

// ---------------- Prep 3: invert E (128) and M (32) — LDS-resident GJ ----------------
__global__ void k_inv_lds() {
  extern __shared__ float smv[];
  float* aug  = smv;            // 128x256
  float* aug2 = smv + 32768;    // 32x64
  __shared__ float col[128];
  float* ws = g_ws;
  const float* E = ws + OFF_E;
  int tid = threadIdx.x;
  for (int idx = tid; idx < 32768; idx += 1024) {
    int i = idx >> 8, j = idx & 255;
    aug[idx] = (j < 128) ? E[i * 128 + j] : ((j - 128) == i ? 1.f : 0.f);
  }
  __syncthreads();
  for (int k = 0; k < 128; ++k) {
    if (tid < 128) col[tid] = aug[tid * 256 + k];
    __syncthreads();
    float d = 1.f / col[k];
    if (tid < 256) aug[k * 256 + tid] *= d;
    __syncthreads();
    int j = tid & 255, iseg = tid >> 8;
    float rkj = aug[k * 256 + j];
    for (int i = iseg * 32; i < iseg * 32 + 32; ++i) {
      if (i == k) continue;
      aug[i * 256 + j] -= col[i] * rkj;
    }
    __syncthreads();
  }
  for (int idx = tid; idx < 16384; idx += 1024) {
    int i = idx >> 7, j = idx & 127;
    ws[OFF_EINV + idx] = aug[i * 256 + 128 + j];
  }
  const float* M = ws + OFF_M;
  for (int idx = tid; idx < 2048; idx += 1024) {
    int i = idx >> 6, j = idx & 63;
    aug2[idx] = (j < 32) ? M[i * 32 + j] : ((j - 32) == i ? 1.f : 0.f);
  }
  __syncthreads();
  for (int k = 0; k < 32; ++k) {
    if (tid < 32) col[tid] = aug2[tid * 64 + k];
    __syncthreads();
    float d = 1.f / col[k];
    if (tid < 64) aug2[k * 64 + tid] *= d;
    __syncthreads();
    if (tid < 64) {
      float rkj = aug2[k * 64 + tid];
      for (int i = 0; i < 32; ++i) if (i != k) aug2[i * 64 + tid] -= col[i] * rkj;
    }
    __syncthreads();
  }
  for (int idx = tid; idx < 1024; idx += 1024) {
    int i = idx >> 5, j = idx & 31;
    ws[OFF_MINV + idx] = aug2[i * 64 + 32 + j];
  }
}

// Fallback: global-scratch GJ
__global__ void k_inv() {
  float* ws = g_ws;
  __shared__ float col[128];
  float* aug = ws + OFF_AUG;
  const float* E = ws + OFF_E;
  int tid = threadIdx.x;
  for (int idx = tid; idx < 32768; idx += 1024) {
    int i = idx >> 8, j = idx & 255;
    aug[idx] = (j < 128) ? E[i * 128 + j] : ((j - 128) == i ? 1.f : 0.f);
  }
  __syncthreads();
  for (int k = 0; k < 128; ++k) {
    if (tid < 128) col[tid] = aug[tid * 256 + k];
    __syncthreads();
    float d = 1.f / col[k];
    if (tid < 256) aug[k * 256 + tid] *= d;
    __syncthreads();
    int j = tid & 255, iseg = tid >> 8;
    float rkj = aug[k * 256 + j];
    for (int i = iseg * 32; i < iseg * 32 + 32; ++i) {
      if (i == k) continue;
      aug[i * 256 + j] -= col[i] * rkj;
    }
    __syncthreads();
  }
  for (int idx = tid; idx < 16384; idx += 1024) {
    int i = idx >> 7, j = idx & 127;
    ws[OFF_EINV + idx] = aug[i * 256 + 128 + j];
  }
  __syncthreads();
  float* aug2 = ws + OFF_AUG2;
  const float* M = ws + OFF_M;
  for (int idx = tid; idx < 2048; idx += 1024) {
    int i = idx >> 6, j = idx & 63;
    aug2[idx] = (j < 32) ? M[i * 32 + j] : ((j - 32) == i ? 1.f : 0.f);
  }
  __syncthreads();
  for (int k = 0; k < 32; ++k) {
    if (tid < 32) col[tid] = aug2[tid * 64 + k];
    __syncthreads();
    float d = 1.f / col[k];
    if (tid < 64) aug2[k * 64 + tid] *= d;
    __syncthreads();
    if (tid < 64) {
      float rkj = aug2[k * 64 + tid];
      for (int i = 0; i < 32; ++i) if (i != k) aug2[i * 64 + tid] -= col[i] * rkj;
    }
    __syncthreads();
  }
  for (int idx = tid; idx < 1024; idx += 1024) {
    int i = idx >> 5, j = idx & 31;
    ws[OFF_MINV + idx] = aug2[i * 64 + 32 + j];
  }
}

// ---------------- Prep 4: Fh, B1h, B2h, W0 ----------------
__global__ void k_fuse(const void* __restrict__ B2, const void* __restrict__ C2) {
  const int f = g_isf32;
  float* ws = g_ws;
  const float* einv = ws + OFF_EINV;
  const float* H = ws + OFF_H;
  const float* minv = ws + OFF_MINV;
  int id = blockIdx.x * 256 + threadIdx.x;   // 40960
  if (id < 16384) {
    int l = id >> 7, j = id & 127;
    float a = 0.f;
    for (int m = 0; m < 128; ++m) a = fmaf(einv[l * 128 + m], H[(256 + m) * 384 + j], a);
    ws[OFF_FH + id] = a;
  } else if (id < 32768) {
    int t = id - 16384; int l = t >> 7, j = t & 127;
    float a = 0.f;
    for (int m = 0; m < 128; ++m) a = fmaf(einv[l * 128 + m], H[(256 + m) * 384 + 128 + j], a);
    ws[OFF_B1H + t] = a;
  } else if (id < 36864) {
    int t = id - 32768; int l = t >> 5, k = t & 31;
    float a = 0.f;
    for (int m = 0; m < 128; ++m) a = fmaf(einv[l * 128 + m], ld(B2, m * 32 + k, f), a);
    ws[OFF_B2H + t] = a;
  } else if (id < 40960) {
    int t = id - 36864; int k = t >> 7, l = t & 127;
    float a = 0.f;
    for (int m = 0; m < 32; ++m) a = fmaf(minv[k * 32 + m], ld(C2, m * 128 + l, f), a);
    ws[OFF_W0 + t] = a;
  }
}

// ---------------- Prep 5: WC ----------------
__global__ void k_w2() {
  float* ws = g_ws;
  const float* H = ws + OFF_H;
  const float* w0 = ws + OFF_W0;
  int id = blockIdx.x * 256 + threadIdx.x;   // 4096
  int k = id >> 7, l = id & 127;
  float a = 0.f;
  for (int m = 0; m < 128; ++m) a = fmaf(w0[k * 128 + m], -H[(128 + l) * 384 + m], a);
  ws[OFF_WC + id] = a;
}

// ---------------- Prep 6: CF = C1 Fh, CB = C1 B1h, CB2 = C1 B2h ----------------
__global__ void k_cf() {
  float* ws = g_ws;
  const float* H = ws + OFF_H;
  int id = blockIdx.x * 256 + threadIdx.x;   // 36864
  if (id < 16384) {
    int l = id >> 7, j = id & 127;
    float a = 0.f;
    for (int m = 0; m < 128; ++m) a = fmaf(-H[(128 + l) * 384 + m], ws[OFF_FH + m * 128 + j], a);
    ws[OFF_CF + id] = a;
  } else if (id < 32768) {
    int t = id - 16384; int l = t >> 7, j = t & 127;
    float a = 0.f;
    for (int m = 0; m < 128; ++m) a = fmaf(-H[(128 + l) * 384 + m], ws[OFF_B1H + m * 128 + j], a);
    ws[OFF_CB + t] = a;
  } else {
    int t = id - 32768; int l = t >> 5, k = t & 31;
    float a = 0.f;
    for (int m = 0; m < 128; ++m) a = fmaf(-H[(128 + l) * 384 + m], ws[OFF_B2H + m * 32 + k], a);
    ws[OFF_CB2 + t] = a;
  }
}

// ---------------- Prep 7: packed/scaled layouts ----------------
__global__ void k_pk(const void* __restrict__ D12, const void* __restrict__ C2,
                     const void* __restrict__ D21, const void* __restrict__ D22) {
  const int f = g_isf32;
  float* ws = g_ws;
  const float* H = ws + OFF_H;
  const float* g = ws + OFF_GL2;
  int id = blockIdx.x * 256 + threadIdx.x;   // 58368
  if (id < 8192) {                   // PF
    int j = id >> 6, l = id & 63;
    ((float2*)(ws + OFF_PF))[id] =
        make_float2(ws[OFF_FH + l * 128 + j], ws[OFF_FH + (l + 64) * 128 + j]);
  } else if (id < 16384) {           // PB
    int t = id - 8192; int j = t >> 6, l = t & 63;
    ((float2*)(ws + OFF_PB))[t] =
        make_float2(ws[OFF_B1H + l * 128 + j], ws[OFF_B1H + (l + 64) * 128 + j]);
  } else if (id < 24576) {           // PCF (gl2-scaled rows)
    int t = id - 16384; int j = t >> 6, l = t & 63;
    ((float2*)(ws + OFF_PCF))[t] =
        make_float2(g[l] * ws[OFF_CF + l * 128 + j], g[l + 64] * ws[OFF_CF + (l + 64) * 128 + j]);
  } else if (id < 32768) {           // PCB
    int t = id - 24576; int j = t >> 6, l = t & 63;
    ((float2*)(ws + OFF_PCB))[t] =
        make_float2(g[l] * ws[OFF_CB + l * 128 + j], g[l + 64] * ws[OFF_CB + (l + 64) * 128 + j]);
  } else if (id < 36864) {           // SAB
    int t = id - 32768; int i = t >> 6, l = t & 63;
    float sx = (i < l) ? -g[l] * H[(128 + l) * 384 + 128 + i] : 0.f;
    float sy = -g[l + 64] * H[(192 + l) * 384 + 128 + i];
    ((float2*)(ws + OFF_SAB))[t] = make_float2(sx, sy);
  } else if (id < 40960) {           // SB2
    int t = id - 36864; int ii = t >> 6, l = t & 63;
    ws[OFF_SB2 + t] = (ii < l) ? -g[l + 64] * H[(192 + l) * 384 + 192 + ii] : 0.f;
  } else if (id < 43008) {           // BUQ
    int t = id - 40960; int k = t >> 6, l = t & 63;
    ((float2*)(ws + OFF_BUQ))[t] =
        make_float2(ws[OFF_B2H + l * 32 + k], ws[OFF_B2H + (l + 64) * 32 + k]);
  } else if (id < 45056) {           // D12Q
    int t = id - 43008; int k = t >> 6, l = t & 63;
    ((float2*)(ws + OFF_D12Q))[t] =
        make_float2(g[l] * ld(D12, l * 32 + k, f), g[l + 64] * ld(D12, (l + 64) * 32 + k, f));
  } else if (id < 47104) {           // SCB2
    int t = id - 45056; int k = t >> 6, l = t & 63;
    ((float2*)(ws + OFF_SCB2))[t] =
        make_float2(g[l] * ws[OFF_CB2 + l * 32 + k], g[l + 64] * ws[OFF_CB2 + (l + 64) * 32 + k]);
  } else if (id < 49152) {           // WCS
    int t = id - 47104; int k = t >> 6, l = t & 63;
    ((float2*)(ws + OFF_WCS))[t] =
        make_float2(g[l] * ws[OFF_WC + k * 128 + l], g[l + 64] * ws[OFF_WC + k * 128 + l + 64]);
  } else if (id < 53248) {           // C2Y
    int t = id - 49152; int m = t >> 5, o = t & 31;
    ws[OFF_C2Y + t] = ld(C2, o * 128 + m, f);
  } else if (id < 57344) {           // D21Y
    int t = id - 53248; int m = t >> 5, o = t & 31;
    ws[OFF_D21Y + t] = ld(D21, o * 128 + m, f);
  } else if (id < 58368) {           // D22Y
    int t = id - 57344; int k = t >> 5, o = t & 31;
    ws[OFF_D22Y + t] = ld(D22, o * 32 + k, f);
  }
}

// ---------------- Prep 8: x0 and a0 ----------------
__global__ void k_x0a0(const void* __restrict__ x0s, const void* __restrict__ u_in) {
  const int f = g_isf32;
  float* ws = g_ws;
  int id = blockIdx.x * 256 + threadIdx.x;   // 49152
  if (id < 32768) {
    int b = id >> 7, l = id & 127;
    float a = 0.f;
    for (int k = 0; k < 32; ++k)
      a = fmaf(ld(x0s, b * 32 + k, f), ws[OFF_W0 + k * 128 + l], a);
    ws[OFF_X0 + id] = a;
  } else {
    int t = id - 32768; int b = t >> 6, lane = t & 63;
    const float2* WCs = (const float2*)(ws + OFF_WCS);
    const float2* D12Q = (const float2*)(ws + OFF_D12Q);
    float ax = 0.f, ay = 0.f;
    for (int k = 0; k < 32; ++k) {
      float yk = ld(x0s, b * 32 + k, f);
      float2 wc = WCs[k * 64 + lane];
      ax = fmaf(wc.x, yk, ax); ay = fmaf(wc.y, yk, ay);
      float u0 = ld(u_in, b * Tn * 32 + k, f);
      float2 dq = D12Q[k * 64 + lane];
      ax = fmaf(dq.x, u0, ax); ay = fmaf(dq.y, u0, ay);
    }
    ((float2*)(ws + OFF_A0))[b * 64 + lane] = make_float2(ax, ay);
  }
}

// ---- y emission from three matrix pointers (global or LDS) ----
DEV void y_emit_p(const float* C2Y, const float* DY, const float* D22Y,
                  float xlv, float xhv, float2 wv, float uyv,
                  int b, int t, int lane, int f, void* out) {
  int o = lane & 31, h = lane >> 5;
  float acc = 0.f;
#pragma unroll 8
  for (int l = 0; l < 64; ++l) {
    float xle = rdlane(xlv, l), xhe = rdlane(xhv, l);
    float xv = h ? xhe : xle;
    acc = fmaf(xv, C2Y[(l + 64 * h) * 32 + o], acc);
  }
#pragma unroll 8
  for (int l = 0; l < 64; ++l) {
    float wxe = rdlane(wv.x, l), wye = rdlane(wv.y, l);
    float wvv = h ? wye : wxe;
    acc = fmaf(wvv, DY[(l + 64 * h) * 32 + o], acc);
  }
  if (h == 0) {
#pragma unroll 8
    for (int k = 0; k < 32; ++k)
      acc = fmaf(rdlane(uyv, k), D22Y[k * 32 + o], acc);
  }
  acc += __shfl_down(acc, 32);
  if (lane < 32) {
    size_t oi = ((size_t)b * Tn + t) * 32 + o;
    if (f) ((float*)out)[oi] = acc;
    else   ((__hip_bfloat16*)out)[oi] = __float2bfloat16(acc);
  }
}

// ---------------- Main kernel: 16 waves (1024 threads), round-2 algebra,
// ONE barrier/step. Cross-wave latency hiding: 4 waves/SIMD instead of 2.
// w0-3  (one per SIMD): s-forwarded tanh chain + 32-col PB/PCB matvec (L2)
//        -> xbuf/abuf slots 0-3. w0 posts (wx,wy) to wbuf[parity].
// w4-11: x-matvec PF/PCF, 16 cols each (32 L2 loads/wave) -> slots 4-11.
// w12:  BUQ*u(t) -> xbuf slot 12 (abuf slot 12 pre-zeroed).
// w13:  SCB2*u(t)+D12Q*u(t+1) -> abuf slot 13 (xbuf slot 13 pre-zeroed).
// w14:  y_emit(t) from LDS-staged C2Y/D21Y/D22Y, reads wbuf[(t-1)&1].
// w15:  idle (barrier participant).
// Reductions: chains sum abuf slots 0..13 -> acc; w4-11 & w14 sum xbuf
// slots 0..13 -> x. Parity double-buffered; all arithmetic f32.
__global__ __launch_bounds__(1024) void k_scan16(const void* __restrict__ u_in,
                                                 const void* __restrict__ x0s,
                                                 void* __restrict__ out) {
  extern __shared__ float sm[];
  float2* sSAB  = (float2*)sm;             // [4096]  32 KB
  float*  sSB2  = sm + 8192;               // [4096]  16 KB
  float2* xbuf  = (float2*)(sm + 12288);   // [2][16][64] 16 KB
  float2* abuf  = (float2*)(sm + 16384);   // [2][16][64] 16 KB
  float2* wbuf  = (float2*)(sm + 20480);   // [2][64]  1 KB
  float*  sC2Y  = sm + 20736;              // [4096]  16 KB
  float*  sD21Y = sm + 24832;              // [4096]  16 KB
  float*  sD22Y = sm + 28928;              // [1024]   4 KB  -> 119808 B total
  const float* ws = g_ws;
  const int f = g_isf32;
  const int tid = threadIdx.x, lane = tid & 63, w = tid >> 6;
  for (int i = tid; i < 4096; i += 1024) sSAB[i] = ((const float2*)(ws + OFF_SAB))[i];
  for (int i = tid; i < 4096; i += 1024) sSB2[i] = ws[OFF_SB2 + i];
  for (int i = tid; i < 4096; i += 1024) sC2Y[i] = ws[OFF_C2Y + i];
  for (int i = tid; i < 4096; i += 1024) sD21Y[i] = ws[OFF_D21Y + i];
  if (tid < 1024) { if (tid < 1024) sD22Y[tid] = ws[OFF_D22Y + tid]; }
  // pre-zero the constant-zero partial slots (both parities)
  if (tid < 64) {
    xbuf[(0 * 16 + 13) * 64 + tid] = make_float2(0.f, 0.f);
    xbuf[(1 * 16 + 13) * 64 + tid] = make_float2(0.f, 0.f);
    abuf[(0 * 16 + 12) * 64 + tid] = make_float2(0.f, 0.f);
    abuf[(1 * 16 + 12) * 64 + tid] = make_float2(0.f, 0.f);
  }

  const int b = blockIdx.x;
  const bool isChain = (w < 4);

  // chain waves: 32-column PB/PCB fragments (L2-resident; compiler may refetch)
  float2 vA[32], vB[32];
  if (isChain) {
    const float2* P1 = (const float2*)(ws + OFF_PB);
    const float2* P2 = (const float2*)(ws + OFF_PCB);
    const int jcol = w * 32;
#pragma unroll
    for (int c = 0; c < 32; ++c) {
      vA[c] = P1[(jcol + c) * 64 + lane];
      vB[c] = P2[(jcol + c) * 64 + lane];
    }
  }
  float xl = ws[OFF_X0 + b * 128 + lane];
  float xh = ws[OFF_X0 + b * 128 + 64 + lane];
  float accx = 0.f, accy = 0.f;
  if (isChain) {
    float2 a2 = ((const float2*)(ws + OFF_A0))[b * 64 + lane];
    accx = a2.x; accy = a2.y;
  }
  // per-role u register buffers
  float ucur = 0.f;           // w12: u(t)
  float u0v = 0.f, u1v = 0.f; // w13: u(t), u(t+1)
  float uyc = 0.f;            // w14: u(t-1)
  if (w == 12 && lane < 32) ucur = ld(u_in, (size_t)b * Tn * 32 + lane, f);
  if (w == 13 && lane < 32) {
    u0v = ld(u_in, (size_t)b * Tn * 32 + lane, f);
    u1v = ld(u_in, ((size_t)b * Tn + 1) * 32 + lane, f);
  }
  if (w == 14 && lane < 32) {  // y(0) = x0_sys row (C2 pinv(C2) = I on row space)
    size_t oi = (size_t)b * Tn * 32 + lane;
    float v = ld(x0s, b * 32 + lane, f);
    if (f) ((float*)out)[oi] = v;
    else   ((__hip_bfloat16*)out)[oi] = __float2bfloat16(v);
  }
  // wave-uniform broadcast-lane bases (SGPR)
  const int jbC = __builtin_amdgcn_readfirstlane((w & 1) * 32);        // chains
  const int jbX = __builtin_amdgcn_readfirstlane(((w - 4) & 3) * 16);  // x-waves
  __syncthreads();

#pragma unroll 1
  for (int t = 0; t < Tn - 1; ++t) {
    const int p = t & 1;
    if (isChain) {
      __builtin_amdgcn_s_setprio(1);
      // --- serial tanh chain, s-forwarded (bit-exact; rounds 3-9 form) ---
      float s = rdlane(accx, 0);
#pragma unroll
      for (int i = 0; i < 64; ++i) {
        float e2 = __builtin_amdgcn_exp2f(s);
        float r  = __builtin_amdgcn_rcpf(1.f + e2);
        float wi = fmaf(-2.f, r, 1.f);
        float2 sp = sSAB[i * 64 + lane];
        if (i < 63) {
          float spn  = rdlane(sp.x, i + 1);
          float sold = rdlane(accx, i + 1);
          s = fmaf(spn, wi, sold);
        }
        accx = fmaf(sp.x, wi, accx);
        accy = fmaf(sp.y, wi, accy);
      }
      float ex = __builtin_amdgcn_exp2f(accx);               // accx now final
      float wxv = fmaf(-2.f, __builtin_amdgcn_rcpf(1.f + ex), 1.f);
      float s2 = rdlane(accy, 0);
#pragma unroll
      for (int i = 0; i < 64; ++i) {
        float e2 = __builtin_amdgcn_exp2f(s2);
        float r  = __builtin_amdgcn_rcpf(1.f + e2);
        float wi = fmaf(-2.f, r, 1.f);
        float sb = sSB2[i * 64 + lane];
        if (i < 63) {
          float spn  = rdlane(sb, i + 1);
          float sold = rdlane(accy, i + 1);
          s2 = fmaf(spn, wi, sold);
        }
        accy = fmaf(sb, wi, accy);
      }
      float ey = __builtin_amdgcn_exp2f(accy);               // accy now final
      float wyv = fmaf(-2.f, __builtin_amdgcn_rcpf(1.f + ey), 1.f);
      if (w == 0) wbuf[p * 64 + lane] = make_float2(wxv, wyv);

      // --- w-matvec over this wave's 32 PB/PCB columns ---
      float px = 0.f, py = 0.f, pax = 0.f, pay = 0.f;
      float wsrc = (w < 2) ? wxv : wyv;
#pragma unroll
      for (int c = 0; c < 32; ++c) {
        float wj = rdlane(wsrc, jbC + c);
        px  = fmaf(vA[c].x, wj, px);
        py  = fmaf(vA[c].y, wj, py);
        pax = fmaf(vB[c].x, wj, pax);
        pay = fmaf(vB[c].y, wj, pay);
      }
      __builtin_amdgcn_s_setprio(0);
      xbuf[(p * 16 + w) * 64 + lane] = make_float2(px, py);
      abuf[(p * 16 + w) * 64 + lane] = make_float2(pax, pay);
      __syncthreads();                                       // the ONLY barrier
      float sax = 0.f, say = 0.f;
#pragma unroll
      for (int w2 = 0; w2 < 14; ++w2) {
        float2 av = abuf[(p * 16 + w2) * 64 + lane];
        sax += av.x; say += av.y;
      }
      accx = sax; accy = say;
    } else if (w < 12) {
      // --- x-matvec: 16 PF/PCF columns ---
      float px = 0.f, py = 0.f, pax = 0.f, pay = 0.f;
      float xsrc = (w < 8) ? xl : xh;
      const int jc = (w - 4) * 16;
      const float2* PF  = (const float2*)(ws + OFF_PF);
      const float2* PCF = (const float2*)(ws + OFF_PCF);
#pragma unroll
      for (int c = 0; c < 16; ++c) {
        float xj = rdlane(xsrc, jbX + c);
        float2 fv = PF [(jc + c) * 64 + lane];
        float2 cv = PCF[(jc + c) * 64 + lane];
        px  = fmaf(fv.x, xj, px);  py  = fmaf(fv.y, xj, py);
        pax = fmaf(cv.x, xj, pax); pay = fmaf(cv.y, xj, pay);
      }
      xbuf[(p * 16 + w) * 64 + lane] = make_float2(px, py);
      abuf[(p * 16 + w) * 64 + lane] = make_float2(pax, pay);
      __syncthreads();
      float sxl = 0.f, sxh = 0.f;
#pragma unroll
      for (int w2 = 0; w2 < 14; ++w2) {
        float2 xv = xbuf[(p * 16 + w2) * 64 + lane];
        sxl += xv.x; sxh += xv.y;
      }
      xl = sxl; xh = sxh;
    } else if (w == 12) {
      // --- BUQ * u(t) -> x partial only ---
      float un = ucur;
      if (lane < 32) un = ld(u_in, ((size_t)b * Tn + t + 1) * 32 + lane, f);
      float px = 0.f, py = 0.f;
      const float2* BUq = (const float2*)(ws + OFF_BUQ);
#pragma unroll 8
      for (int k = 0; k < 32; ++k) {
        float uk = rdlane(ucur, k);
        float2 bu = BUq[k * 64 + lane];
        px = fmaf(bu.x, uk, px); py = fmaf(bu.y, uk, py);
      }
      ucur = un;
      xbuf[(p * 16 + 12) * 64 + lane] = make_float2(px, py);
      __syncthreads();
    } else if (w == 13) {
      // --- SCB2*u(t) + D12Q*u(t+1) -> acc partial only ---
      float u2v = u1v;
      if (lane < 32 && t + 2 < Tn) u2v = ld(u_in, ((size_t)b * Tn + t + 2) * 32 + lane, f);
      float pax = 0.f, pay = 0.f;
      const float2* SC = (const float2*)(ws + OFF_SCB2);
      const float2* DQ = (const float2*)(ws + OFF_D12Q);
#pragma unroll 8
      for (int k = 0; k < 32; ++k) {
        float u0k = rdlane(u0v, k);
        float2 sc = SC[k * 64 + lane];
        pax = fmaf(sc.x, u0k, pax); pay = fmaf(sc.y, u0k, pay);
        float u1k = rdlane(u1v, k);
        float2 dq = DQ[k * 64 + lane];
        pax = fmaf(dq.x, u1k, pax); pay = fmaf(dq.y, u1k, pay);
      }
      u0v = u1v; u1v = u2v;
      abuf[(p * 16 + 13) * 64 + lane] = make_float2(pax, pay);
      __syncthreads();
    } else if (w == 14) {
      // --- output GEMM y(t) from LDS matrices ---
      float uyn = uyc;
      if (lane < 32) uyn = ld(u_in, ((size_t)b * Tn + t) * 32 + lane, f);
      if (t >= 1) {
        float2 wv = wbuf[((t - 1) & 1) * 64 + lane];         // w(t-1)
        y_emit_p(sC2Y, sD21Y, sD22Y, xl, xh, wv, uyc, b, t, lane, f, out);
      }
      uyc = uyn;
      __syncthreads();
      float sxl = 0.f, sxh = 0.f;
#pragma unroll
      for (int w2 = 0; w2 < 14; ++w2) {
        float2 xv = xbuf[(p * 16 + w2) * 64 + lane];
        sxl += xv.x; sxh += xv.y;
      }
      xl = sxl; xh = sxh;
    } else { // w == 15: idle barrier participant
      __syncthreads();
    }
  }
  // epilogue: y(1023) from x(1023), w(1022), u(1022)
  if (w == 14) {
    float2 wv = wbuf[((Tn - 2) & 1) * 64 + lane];
    y_emit_p(sC2Y, sD21Y, sD22Y, xl, xh, wv, uyc, b, Tn - 1, lane, f, out);
  }
}

// ---------------- Fallback main kernel: round-2 static-LDS version (verified) ----
__global__ __launch_bounds__(512) void k_scan8_fb(const void* __restrict__ u_in,
                                                  const void* __restrict__ x0s,
                                                  void* __restrict__ out) {
  __shared__ float2 sSAB[64 * 64];
  __shared__ float  sSB2[64 * 64];
  __shared__ float2 xbuf[2][8][64];
  __shared__ float2 abuf[2][8][64];
  const float* ws = g_ws;
  const int f = g_isf32;
  const int tid = threadIdx.x, lane = tid & 63, w = tid >> 6;
  for (int i = tid; i < 4096; i += 512) sSAB[i] = ((const float2*)(ws + OFF_SAB))[i];
  for (int i = tid; i < 4096; i += 512) sSB2[i] = ws[OFF_SB2 + i];

  const int b = blockIdx.x;
  const bool isScan = (w < 4);
  float2 vA[32], vB[32];
  if (isScan) {
    const float2* P1 = (const float2*)(ws + OFF_PB);
    const float2* P2 = (const float2*)(ws + OFF_PCB);
    const int jcol = (w & 3) * 32;
#pragma unroll
    for (int c = 0; c < 32; ++c) {
      vA[c] = P1[(jcol + c) * 64 + lane];
      vB[c] = P2[(jcol + c) * 64 + lane];
    }
  }
  float xl = ws[OFF_X0 + b * 128 + lane];
  float xh = ws[OFF_X0 + b * 128 + 64 + lane];
  float2 a2 = ((const float2*)(ws + OFF_A0))[b * 64 + lane];
  float accx = a2.x, accy = a2.y;
  float ucur = 0.f;
  float u0v = 0.f, u1v = 0.f;
  float uyc = 0.f;
  if (w == 4 && lane < 32) ucur = ld(u_in, (size_t)b * Tn * 32 + lane, f);
  if (w == 6 && lane < 32) {
    u0v = ld(u_in, (size_t)b * Tn * 32 + lane, f);
    u1v = ld(u_in, ((size_t)b * Tn + 1) * 32 + lane, f);
  }
  if (w == 6) { xbuf[0][6][lane] = make_float2(0.f, 0.f); xbuf[1][6][lane] = make_float2(0.f, 0.f); }
  if (w == 7 && lane < 32) {
    size_t oi = (size_t)b * Tn * 32 + lane;
    float v = ld(x0s, b * 32 + lane, f);
    if (f) ((float*)out)[oi] = v;
    else   ((__hip_bfloat16*)out)[oi] = __float2bfloat16(v);
  }
  const int jb = __builtin_amdgcn_readfirstlane((w & 1) * 32);
  __syncthreads();

#pragma unroll 1
  for (int t = 0; t < Tn - 1; ++t) {
    const int p = t & 1;
    if (isScan) {
      __builtin_amdgcn_s_setprio(1);
#pragma unroll
      for (int i = 0; i < 64; ++i) {
        float s = rdlane(accx, i);
        float e2 = __builtin_amdgcn_exp2f(s);
        float wi = fmaf(-2.f, __builtin_amdgcn_rcpf(1.f + e2), 1.f);
        float2 sp = sSAB[i * 64 + lane];
        accx = fmaf(sp.x, wi, accx);
        accy = fmaf(sp.y, wi, accy);
      }
      float ex = __builtin_amdgcn_exp2f(accx);
      float wx = fmaf(-2.f, __builtin_amdgcn_rcpf(1.f + ex), 1.f);
#pragma unroll
      for (int i = 0; i < 64; ++i) {
        float s = rdlane(accy, i);
        float e2 = __builtin_amdgcn_exp2f(s);
        float wi = fmaf(-2.f, __builtin_amdgcn_rcpf(1.f + e2), 1.f);
        accy = fmaf(sSB2[i * 64 + lane], wi, accy);
      }
      float ey = __builtin_amdgcn_exp2f(accy);
      float wy = fmaf(-2.f, __builtin_amdgcn_rcpf(1.f + ey), 1.f);
      if (w == 0) xbuf[p][7][lane] = make_float2(wx, wy);

      float px = 0.f, py = 0.f, pax = 0.f, pay = 0.f;
      float wsrc = (w < 2) ? wx : wy;
#pragma unroll
      for (int c = 0; c < 32; ++c) {
        float wj = rdlane(wsrc, jb + c);
        px  = fmaf(vA[c].x, wj, px);
        py  = fmaf(vA[c].y, wj, py);
        pax = fmaf(vB[c].x, wj, pax);
        pay = fmaf(vB[c].y, wj, pay);
      }
      __builtin_amdgcn_s_setprio(0);
      xbuf[p][w][lane] = make_float2(px, py);
      abuf[p][w][lane] = make_float2(pax, pay);
      __syncthreads();
      float sax = 0.f, say = 0.f;
#pragma unroll
      for (int w2 = 0; w2 < 7; ++w2) {
        float2 av = abuf[p][w2][lane];
        sax += av.x; say += av.y;
      }
      accx = sax; accy = say;
    } else if (w == 4) {
      float un = ucur;
      if (lane < 32) un = ld(u_in, ((size_t)b * Tn + t + 1) * 32 + lane, f);
      float px = 0.f, py = 0.f, pax = 0.f, pay = 0.f;
      const float2* BUq = (const float2*)(ws + OFF_BUQ);
#pragma unroll 8
      for (int k = 0; k < 32; ++k) {
        float uk = rdlane(ucur, k);
        float2 bu = BUq[k * 64 + lane];
        px = fmaf(bu.x, uk, px); py = fmaf(bu.y, uk, py);
      }
      const float2* PF = (const float2*)(ws + OFF_PF);
      const float2* PCF = (const float2*)(ws + OFF_PCF);
#pragma unroll 8
      for (int c = 0; c < 64; ++c) {
        float xj = rdlane(xl, c);
        float2 fv = PF[c * 64 + lane];
        float2 cv = PCF[c * 64 + lane];
        px  = fmaf(fv.x, xj, px);  py  = fmaf(fv.y, xj, py);
        pax = fmaf(cv.x, xj, pax); pay = fmaf(cv.y, xj, pay);
      }
      ucur = un;
      xbuf[p][4][lane] = make_float2(px, py);
      abuf[p][4][lane] = make_float2(pax, pay);
      __syncthreads();
      float sxl = 0.f, sxh = 0.f;
#pragma unroll
      for (int w2 = 0; w2 < 7; ++w2) {
        float2 xv = xbuf[p][w2][lane];
        sxl += xv.x; sxh += xv.y;
      }
      xl = sxl; xh = sxh;
    } else if (w == 5) {
      float px = 0.f, py = 0.f, pax = 0.f, pay = 0.f;
      const float2* PF = (const float2*)(ws + OFF_PF);
      const float2* PCF = (const float2*)(ws + OFF_PCF);
#pragma unroll 8
      for (int c = 0; c < 64; ++c) {
        float xj = rdlane(xh, c);
        float2 fv = PF[(64 + c) * 64 + lane];
        float2 cv = PCF[(64 + c) * 64 + lane];
        px  = fmaf(fv.x, xj, px);  py  = fmaf(fv.y, xj, py);
        pax = fmaf(cv.x, xj, pax); pay = fmaf(cv.y, xj, pay);
      }
      xbuf[p][5][lane] = make_float2(px, py);
      abuf[p][5][lane] = make_float2(pax, pay);
      __syncthreads();
      float sxl = 0.f, sxh = 0.f;
#pragma unroll
      for (int w2 = 0; w2 < 7; ++w2) {
        float2 xv = xbuf[p][w2][lane];
        sxl += xv.x; sxh += xv.y;
      }
      xl = sxl; xh = sxh;
    } else if (w == 6) {
      float u2v = u1v;
      if (lane < 32 && t + 2 < Tn) u2v = ld(u_in, ((size_t)b * Tn + t + 2) * 32 + lane, f);
      float pax = 0.f, pay = 0.f;
      const float2* SC = (const float2*)(ws + OFF_SCB2);
      const float2* DQ = (const float2*)(ws + OFF_D12Q);
#pragma unroll 8
      for (int k = 0; k < 32; ++k) {
        float u0k = rdlane(u0v, k);
        float2 sc = SC[k * 64 + lane];
        pax = fmaf(sc.x, u0k, pax); pay = fmaf(sc.y, u0k, pay);
        float u1k = rdlane(u1v, k);
        float2 dq = DQ[k * 64 + lane];
        pax = fmaf(dq.x, u1k, pax); pay = fmaf(dq.y, u1k, pay);
      }
      u0v = u1v; u1v = u2v;
      abuf[p][6][lane] = make_float2(pax, pay);
      __syncthreads();
      float sxl = 0.f, sxh = 0.f;
#pragma unroll
      for (int w2 = 0; w2 < 7; ++w2) {
        float2 xv = xbuf[p][w2][lane];
        sxl += xv.x; sxh += xv.y;
      }
      xl = sxl; xh = sxh;
    } else { // w == 7
      float uyn = uyc;
      if (lane < 32) uyn = ld(u_in, ((size_t)b * Tn + t) * 32 + lane, f);
      if (t >= 1) {
        float2 wv = xbuf[(t - 1) & 1][7][lane];
        y_emit_p(ws + OFF_C2Y, ws + OFF_D21Y, ws + OFF_D22Y,
                 xl, xh, wv, uyc, b, t, lane, f, out);
      }
      uyc = uyn;
      __syncthreads();
      float sxl = 0.f, sxh = 0.f;
#pragma unroll
      for (int w2 = 0; w2 < 7; ++w2) {
        float2 xv = xbuf[p][w2][lane];
        sxl += xv.x; sxh += xv.y;
      }
      xl = sxl; xh = sxh;
    }
  }
  if (w == 7) {
    float2 wv = xbuf[(Tn - 2) & 1][7][lane];
    y_emit_p(ws + OFF_C2Y, ws + OFF_D21Y, ws + OFF_D22Y,
             xl, xh, wv, uyc, b, Tn - 1, lane, f, out);
  }
}

extern "C" void kernel_launch(void* const* d_in, const int* in_sizes, int n_in,
                              void* d_out, int out_size, void* d_ws, size_t ws_size,
                              hipStream_t stream) {
  const void* x0s = d_in[0];
  const void* u   = d_in[1];
  const void* X   = d_in[2];
  const void* Y   = d_in[3];
  const void* B2  = d_in[4];
  const void* C2  = d_in[5];
  const void* D21 = d_in[6];
  const void* D22 = d_in[7];
  const void* D12 = d_in[8];
  (void)d_ws; (void)ws_size; (void)in_sizes; (void)n_in; (void)out_size;

  hipLaunchKernelGGL(k_detect,  dim3(1),     dim3(64),   0, stream, X);
  hipLaunchKernelGGL(k_H,       dim3(576),   dim3(256),  0, stream, X);
  hipLaunchKernelGGL(k_derived, dim3(69),    dim3(256),  0, stream, Y, C2);

  hipError_t e = hipFuncSetAttribute((const void*)k_inv_lds,
                                     hipFuncAttributeMaxDynamicSharedMemorySize,
                                     139264);
  if (e == hipSuccess) {
    hipLaunchKernelGGL(k_inv_lds, dim3(1), dim3(1024), 139264, stream);
  } else {
    (void)hipGetLastError();
    hipLaunchKernelGGL(k_inv,     dim3(1), dim3(1024), 0, stream);
  }

  hipLaunchKernelGGL(k_fuse,    dim3(160),   dim3(256),  0, stream, B2, C2);
  hipLaunchKernelGGL(k_w2,      dim3(16),    dim3(256),  0, stream);
  hipLaunchKernelGGL(k_cf,      dim3(144),   dim3(256),  0, stream);
  hipLaunchKernelGGL(k_pk,      dim3(228),   dim3(256),  0, stream, D12, C2, D21, D22);
  hipLaunchKernelGGL(k_x0a0,    dim3(192),   dim3(256),  0, stream, x0s, u);

  hipError_t e2 = hipFuncSetAttribute((const void*)k_scan16,
                                      hipFuncAttributeMaxDynamicSharedMemorySize,
                                      119808);
  if (e2 == hipSuccess) {
    hipLaunchKernelGGL(k_scan16, dim3(256), dim3(1024), 119808, stream, u, x0s, d_out);
  } else {
    (void)hipGetLastError();
    hipLaunchKernelGGL(k_scan8_fb, dim3(256), dim3(512), 0, stream, u, x0s, d_out);
  }
}

// Round 12
// 6040.894 us; speedup vs baseline: 3.0097x; 3.0097x over previous
//
#include <hip/hip_runtime.h>
#include <hip/hip_bf16.h>

#define DEV static __device__ __forceinline__

constexpr int Tn = 1024;
constexpr float LOG2E = 1.4426950408889634f;

// ---- g_ws float offsets ----
constexpr int OFF_H     = 0;        // 384*384
constexpr int OFF_E     = 147456;   // 16384
constexpr int OFF_EINV  = 163840;   // 16384
constexpr int OFF_M     = 180224;   // 1024
constexpr int OFF_MINV  = 181248;   // 1024
constexpr int OFF_GL2   = 182272;   // 128: (2/lam)*log2e
constexpr int OFF_FH    = 182400;   // 16384  Fh = Einv H31
constexpr int OFF_B1H   = 198784;   // 16384  B1h = Einv H32
constexpr int OFF_B2H   = 215168;   // 4096   B2h = Einv B2
constexpr int OFF_W0    = 219264;   // 4096   W0 = Minv C2
constexpr int OFF_WC    = 223360;   // 4096
constexpr int OFF_CF    = 227456;   // 16384  CF = C1 Fh
constexpr int OFF_CB    = 243840;   // 16384  CB = C1 B1h
constexpr int OFF_CB2   = 260224;   // 4096   CB2 = C1 B2h
constexpr int OFF_PF    = 264320;   // 16384 (8192 f2) PF[j][l]=(Fh[l][j],Fh[l+64][j])
constexpr int OFF_PB    = 280704;   // 16384 B1h pairs
constexpr int OFF_PCF   = 297088;   // 16384 gl2-scaled CF pairs
constexpr int OFF_PCB   = 313472;   // 16384 gl2-scaled CB pairs
constexpr int OFF_SAB   = 329856;   // 8192  (4096 f2) scan couplings lower
constexpr int OFF_SB2   = 338048;   // 4096            scan couplings upper
constexpr int OFF_BUQ   = 342144;   // 4096 (2048 f2)
constexpr int OFF_D12Q  = 346240;   // 4096 gl2-scaled D12 pairs
constexpr int OFF_SCB2  = 350336;   // 4096 gl2-scaled CB2 pairs
constexpr int OFF_WCS   = 354432;   // 4096
constexpr int OFF_C2Y   = 358528;   // 4096  C2Y[m][o] = C2[o][m]
constexpr int OFF_D21Y  = 362624;   // 4096
constexpr int OFF_D22Y  = 366720;   // 1024
constexpr int OFF_AUG   = 367744;   // 32768
constexpr int OFF_AUG2  = 400512;   // 2048
constexpr int OFF_X0    = 402560;   // 32768
constexpr int OFF_A0    = 435328;   // 32768
constexpr int WS_FLOATS = 468096;

__device__ __align__(16) float g_ws[WS_FLOATS];
__device__ int g_isf32;
__device__ float4 g_Q [256 * 1024 * 64];
__device__ float2 g_Xs[256 * 1024 * 64];
__device__ float2 g_Ws[256 * 1024 * 64];

DEV float ld(const void* p, size_t i, int f) {
  return f ? ((const float*)p)[i]
           : __bfloat162float(((const __hip_bfloat16*)p)[i]);
}
DEV float rdlane(float v, int l) {
  return __int_as_float(__builtin_amdgcn_readlane(__float_as_int(v), l));
}

// ---------------- Prep 0: detect input dtype ----------------
__global__ void k_detect(const void* __restrict__ X) {
  if (threadIdx.x == 0) {
    const __hip_bfloat16* p = (const __hip_bfloat16*)X;
    int bad = 0;
    for (int i = 0; i < 512; ++i) {
      float v = __bfloat162float(p[i]);
      if (!(v > -1e6f && v < 1e6f)) bad++;
    }
    g_isf32 = (bad > 0) ? 1 : 0;
  }
}

// ---------------- Prep 1: H = X^T X + eps I ----------------
__global__ void k_H(const void* __restrict__ X) {
  const int f = g_isf32;
  float* ws = g_ws;
  int id = blockIdx.x * 256 + threadIdx.x;   // 147456
  int r = id / 384, c = id % 384;
  float acc = 0.f;
  for (int k = 0; k < 384; ++k)
    acc = fmaf(ld(X, k * 384 + r, f), ld(X, k * 384 + c, f), acc);
  if (r == c) acc += 0.001f;
  ws[OFF_H + id] = acc;
}

// ---------------- Prep 2: E, gl2, M ----------------
__global__ void k_derived(const void* __restrict__ Y, const void* __restrict__ C2) {
  const int f = g_isf32;
  float* ws = g_ws;
  const float* H = ws + OFF_H;
  int id = blockIdx.x * 256 + threadIdx.x;
  if (id < 16384) {
    int i = id >> 7, j = id & 127;
    ws[OFF_E + id] = 0.5f * (H[i * 384 + j] + H[(256 + i) * 384 + 256 + j]
                             + ld(Y, i * 128 + j, f) - ld(Y, j * 128 + i, f));
  } else if (id < 16512) {
    int i = id - 16384;
    ws[OFF_GL2 + i] = LOG2E * 4.f / H[(128 + i) * 384 + 128 + i];
  } else if (id < 17536) {
    int t = id - 16512; int a = t >> 5, b = t & 31;
    float acc = 0.f;
    for (int j = 0; j < 128; ++j)
      acc = fmaf(ld(C2, a * 128 + j, f), ld(C2, b * 128 + j, f), acc);
    ws[OFF_M + t] = acc;
  }
}

// ---------------- Prep 3: invert E (128) and M (32) — LDS-resident GJ ----------------
__global__ void k_inv_lds() {
  extern __shared__ float smv[];
  float* aug  = smv;            // 128x256
  float* aug2 = smv + 32768;    // 32x64
  __shared__ float col[128];
  float* ws = g_ws;
  const float* E = ws + OFF_E;
  int tid = threadIdx.x;
  for (int idx = tid; idx < 32768; idx += 1024) {
    int i = idx >> 8, j = idx & 255;
    aug[idx] = (j < 128) ? E[i * 128 + j] : ((j - 128) == i ? 1.f : 0.f);
  }
  __syncthreads();
  for (int k = 0; k < 128; ++k) {
    if (tid < 128) col[tid] = aug[tid * 256 + k];
    __syncthreads();
    float d = 1.f / col[k];
    if (tid < 256) aug[k * 256 + tid] *= d;
    __syncthreads();
    int j = tid & 255, iseg = tid >> 8;
    float rkj = aug[k * 256 + j];
    for (int i = iseg * 32; i < iseg * 32 + 32; ++i) {
      if (i == k) continue;
      aug[i * 256 + j] -= col[i] * rkj;
    }
    __syncthreads();
  }
  for (int idx = tid; idx < 16384; idx += 1024) {
    int i = idx >> 7, j = idx & 127;
    ws[OFF_EINV + idx] = aug[i * 256 + 128 + j];
  }
  const float* M = ws + OFF_M;
  for (int idx = tid; idx < 2048; idx += 1024) {
    int i = idx >> 6, j = idx & 63;
    aug2[idx] = (j < 32) ? M[i * 32 + j] : ((j - 32) == i ? 1.f : 0.f);
  }
  __syncthreads();
  for (int k = 0; k < 32; ++k) {
    if (tid < 32) col[tid] = aug2[tid * 64 + k];
    __syncthreads();
    float d = 1.f / col[k];
    if (tid < 64) aug2[k * 64 + tid] *= d;
    __syncthreads();
    if (tid < 64) {
      float rkj = aug2[k * 64 + tid];
      for (int i = 0; i < 32; ++i) if (i != k) aug2[i * 64 + tid] -= col[i] * rkj;
    }
    __syncthreads();
  }
  for (int idx = tid; idx < 1024; idx += 1024) {
    int i = idx >> 5, j = idx & 31;
    ws[OFF_MINV + idx] = aug2[i * 64 + 32 + j];
  }
}

// Fallback: global-scratch GJ
__global__ void k_inv() {
  float* ws = g_ws;
  __shared__ float col[128];
  float* aug = ws + OFF_AUG;
  const float* E = ws + OFF_E;
  int tid = threadIdx.x;
  for (int idx = tid; idx < 32768; idx += 1024) {
    int i = idx >> 8, j = idx & 255;
    aug[idx] = (j < 128) ? E[i * 128 + j] : ((j - 128) == i ? 1.f : 0.f);
  }
  __syncthreads();
  for (int k = 0; k < 128; ++k) {
    if (tid < 128) col[tid] = aug[tid * 256 + k];
    __syncthreads();
    float d = 1.f / col[k];
    if (tid < 256) aug[k * 256 + tid] *= d;
    __syncthreads();
    int j = tid & 255, iseg = tid >> 8;
    float rkj = aug[k * 256 + j];
    for (int i = iseg * 32; i < iseg * 32 + 32; ++i) {
      if (i == k) continue;
      aug[i * 256 + j] -= col[i] * rkj;
    }
    __syncthreads();
  }
  for (int idx = tid; idx < 16384; idx += 1024) {
    int i = idx >> 7, j = idx & 127;
    ws[OFF_EINV + idx] = aug[i * 256 + 128 + j];
  }
  __syncthreads();
  float* aug2 = ws + OFF_AUG2;
  const float* M = ws + OFF_M;
  for (int idx = tid; idx < 2048; idx += 1024) {
    int i = idx >> 6, j = idx & 63;
    aug2[idx] = (j < 32) ? M[i * 32 + j] : ((j - 32) == i ? 1.f : 0.f);
  }
  __syncthreads();
  for (int k = 0; k < 32; ++k) {
    if (tid < 32) col[tid] = aug2[tid * 64 + k];
    __syncthreads();
    float d = 1.f / col[k];
    if (tid < 64) aug2[k * 64 + tid] *= d;
    __syncthreads();
    if (tid < 64) {
      float rkj = aug2[k * 64 + tid];
      for (int i = 0; i < 32; ++i) if (i != k) aug2[i * 64 + tid] -= col[i] * rkj;
    }
    __syncthreads();
  }
  for (int idx = tid; idx < 1024; idx += 1024) {
    int i = idx >> 5, j = idx & 31;
    ws[OFF_MINV + idx] = aug2[i * 64 + 32 + j];
  }
}

// ---------------- Prep 4: Fh, B1h, B2h, W0 ----------------
__global__ void k_fuse(const void* __restrict__ B2, const void* __restrict__ C2) {
  const int f = g_isf32;
  float* ws = g_ws;
  const float* einv = ws + OFF_EINV;
  const float* H = ws + OFF_H;
  const float* minv = ws + OFF_MINV;
  int id = blockIdx.x * 256 + threadIdx.x;   // 40960
  if (id < 16384) {
    int l = id >> 7, j = id & 127;
    float a = 0.f;
    for (int m = 0; m < 128; ++m) a = fmaf(einv[l * 128 + m], H[(256 + m) * 384 + j], a);
    ws[OFF_FH + id] = a;
  } else if (id < 32768) {
    int t = id - 16384; int l = t >> 7, j = t & 127;
    float a = 0.f;
    for (int m = 0; m < 128; ++m) a = fmaf(einv[l * 128 + m], H[(256 + m) * 384 + 128 + j], a);
    ws[OFF_B1H + t] = a;
  } else if (id < 36864) {
    int t = id - 32768; int l = t >> 5, k = t & 31;
    float a = 0.f;
    for (int m = 0; m < 128; ++m) a = fmaf(einv[l * 128 + m], ld(B2, m * 32 + k, f), a);
    ws[OFF_B2H + t] = a;
  } else if (id < 40960) {
    int t = id - 36864; int k = t >> 7, l = t & 127;
    float a = 0.f;
    for (int m = 0; m < 32; ++m) a = fmaf(minv[k * 32 + m], ld(C2, m * 128 + l, f), a);
    ws[OFF_W0 + t] = a;
  }
}

// ---------------- Prep 5: WC ----------------
__global__ void k_w2() {
  float* ws = g_ws;
  const float* H = ws + OFF_H;
  const float* w0 = ws + OFF_W0;
  int id = blockIdx.x * 256 + threadIdx.x;   // 4096
  int k = id >> 7, l = id & 127;
  float a = 0.f;
  for (int m = 0; m < 128; ++m) a = fmaf(w0[k * 128 + m], -H[(128 + l) * 384 + m], a);
  ws[OFF_WC + id] = a;
}

// ---------------- Prep 6: CF = C1 Fh, CB = C1 B1h, CB2 = C1 B2h ----------------
__global__ void k_cf() {
  float* ws = g_ws;
  const float* H = ws + OFF_H;
  int id = blockIdx.x * 256 + threadIdx.x;   // 36864
  if (id < 16384) {
    int l = id >> 7, j = id & 127;
    float a = 0.f;
    for (int m = 0; m < 128; ++m) a = fmaf(-H[(128 + l) * 384 + m], ws[OFF_FH + m * 128 + j], a);
    ws[OFF_CF + id] = a;
  } else if (id < 32768) {
    int t = id - 16384; int l = t >> 7, j = t & 127;
    float a = 0.f;
    for (int m = 0; m < 128; ++m) a = fmaf(-H[(128 + l) * 384 + m], ws[OFF_B1H + m * 128 + j], a);
    ws[OFF_CB + t] = a;
  } else {
    int t = id - 32768; int l = t >> 5, k = t & 31;
    float a = 0.f;
    for (int m = 0; m < 128; ++m) a = fmaf(-H[(128 + l) * 384 + m], ws[OFF_B2H + m * 32 + k], a);
    ws[OFF_CB2 + t] = a;
  }
}

// ---------------- Prep 7: packed/scaled layouts ----------------
__global__ void k_pk(const void* __restrict__ D12, const void* __restrict__ C2,
                     const void* __restrict__ D21, const void* __restrict__ D22) {
  const int f = g_isf32;
  float* ws = g_ws;
  const float* H = ws + OFF_H;
  const float* g = ws + OFF_GL2;
  int id = blockIdx.x * 256 + threadIdx.x;   // 58368
  if (id < 8192) {                   // PF
    int j = id >> 6, l = id & 63;
    ((float2*)(ws + OFF_PF))[id] =
        make_float2(ws[OFF_FH + l * 128 + j], ws[OFF_FH + (l + 64) * 128 + j]);
  } else if (id < 16384) {           // PB
    int t = id - 8192; int j = t >> 6, l = t & 63;
    ((float2*)(ws + OFF_PB))[t] =
        make_float2(ws[OFF_B1H + l * 128 + j], ws[OFF_B1H + (l + 64) * 128 + j]);
  } else if (id < 24576) {           // PCF (gl2-scaled rows)
    int t = id - 16384; int j = t >> 6, l = t & 63;
    ((float2*)(ws + OFF_PCF))[t] =
        make_float2(g[l] * ws[OFF_CF + l * 128 + j], g[l + 64] * ws[OFF_CF + (l + 64) * 128 + j]);
  } else if (id < 32768) {           // PCB
    int t = id - 24576; int j = t >> 6, l = t & 63;
    ((float2*)(ws + OFF_PCB))[t] =
        make_float2(g[l] * ws[OFF_CB + l * 128 + j], g[l + 64] * ws[OFF_CB + (l + 64) * 128 + j]);
  } else if (id < 36864) {           // SAB
    int t = id - 32768; int i = t >> 6, l = t & 63;
    float sx = (i < l) ? -g[l] * H[(128 + l) * 384 + 128 + i] : 0.f;
    float sy = -g[l + 64] * H[(192 + l) * 384 + 128 + i];
    ((float2*)(ws + OFF_SAB))[t] = make_float2(sx, sy);
  } else if (id < 40960) {           // SB2
    int t = id - 36864; int ii = t >> 6, l = t & 63;
    ws[OFF_SB2 + t] = (ii < l) ? -g[l + 64] * H[(192 + l) * 384 + 192 + ii] : 0.f;
  } else if (id < 43008) {           // BUQ
    int t = id - 40960; int k = t >> 6, l = t & 63;
    ((float2*)(ws + OFF_BUQ))[t] =
        make_float2(ws[OFF_B2H + l * 32 + k], ws[OFF_B2H + (l + 64) * 32 + k]);
  } else if (id < 45056) {           // D12Q
    int t = id - 43008; int k = t >> 6, l = t & 63;
    ((float2*)(ws + OFF_D12Q))[t] =
        make_float2(g[l] * ld(D12, l * 32 + k, f), g[l + 64] * ld(D12, (l + 64) * 32 + k, f));
  } else if (id < 47104) {           // SCB2
    int t = id - 45056; int k = t >> 6, l = t & 63;
    ((float2*)(ws + OFF_SCB2))[t] =
        make_float2(g[l] * ws[OFF_CB2 + l * 32 + k], g[l + 64] * ws[OFF_CB2 + (l + 64) * 32 + k]);
  } else if (id < 49152) {           // WCS
    int t = id - 47104; int k = t >> 6, l = t & 63;
    ((float2*)(ws + OFF_WCS))[t] =
        make_float2(g[l] * ws[OFF_WC + k * 128 + l], g[l + 64] * ws[OFF_WC + k * 128 + l + 64]);
  } else if (id < 53248) {           // C2Y
    int t = id - 49152; int m = t >> 5, o = t & 31;
    ws[OFF_C2Y + t] = ld(C2, o * 128 + m, f);
  } else if (id < 57344) {           // D21Y
    int t = id - 53248; int m = t >> 5, o = t & 31;
    ws[OFF_D21Y + t] = ld(D21, o * 128 + m, f);
  } else if (id < 58368) {           // D22Y
    int t = id - 57344; int k = t >> 5, o = t & 31;
    ws[OFF_D22Y + t] = ld(D22, o * 32 + k, f);
  }
}

// ---------------- Prep 8: x0 and a0 ----------------
__global__ void k_x0a0(const void* __restrict__ x0s, const void* __restrict__ u_in) {
  const int f = g_isf32;
  float* ws = g_ws;
  int id = blockIdx.x * 256 + threadIdx.x;   // 49152
  if (id < 32768) {
    int b = id >> 7, l = id & 127;
    float a = 0.f;
    for (int k = 0; k < 32; ++k)
      a = fmaf(ld(x0s, b * 32 + k, f), ws[OFF_W0 + k * 128 + l], a);
    ws[OFF_X0 + id] = a;
  } else {
    int t = id - 32768; int b = t >> 6, lane = t & 63;
    const float2* WCs = (const float2*)(ws + OFF_WCS);
    const float2* D12Q = (const float2*)(ws + OFF_D12Q);
    float ax = 0.f, ay = 0.f;
    for (int k = 0; k < 32; ++k) {
      float yk = ld(x0s, b * 32 + k, f);
      float2 wc = WCs[k * 64 + lane];
      ax = fmaf(wc.x, yk, ax); ay = fmaf(wc.y, yk, ay);
      float u0 = ld(u_in, b * Tn * 32 + k, f);
      float2 dq = D12Q[k * 64 + lane];
      ax = fmaf(dq.x, u0, ax); ay = fmaf(dq.y, u0, ay);
    }
    ((float2*)(ws + OFF_A0))[b * 64 + lane] = make_float2(ax, ay);
  }
}

// ---------------- Prep 9: u-injection stream, BLOCKED (1 block/batch-row,
// LDS-staged tables, coalesced u loads + readlane broadcast).
// FP values and fma order identical to the round-1 k_q -> bit-identical g_Q.
__global__ __launch_bounds__(512) void k_q2(const void* __restrict__ u_in) {
  __shared__ float2 sBUQ[2048], sSCB2[2048], sD12Q[2048];   // 48 KB
  const float* ws = g_ws;
  const int f = g_isf32;
  const int tid = threadIdx.x, lane = tid & 63, w = tid >> 6;
  for (int i = tid; i < 2048; i += 512) {
    sBUQ[i]  = ((const float2*)(ws + OFF_BUQ))[i];
    sSCB2[i] = ((const float2*)(ws + OFF_SCB2))[i];
    sD12Q[i] = ((const float2*)(ws + OFF_D12Q))[i];
  }
  __syncthreads();
  const int b = blockIdx.x;
  for (int t = w; t < Tn - 1; t += 8) {
    float uc = 0.f, un = 0.f;
    if (lane < 32) {
      uc = ld(u_in, ((size_t)b * Tn + t) * 32 + lane, f);
      un = ld(u_in, ((size_t)b * Tn + t + 1) * 32 + lane, f);
    }
    float bx = 0.f, by = 0.f, ax = 0.f, ay = 0.f;
#pragma unroll 8
    for (int k = 0; k < 32; ++k) {
      float u0 = rdlane(uc, k);
      float2 bu = sBUQ[k * 64 + lane];
      bx = fmaf(bu.x, u0, bx); by = fmaf(bu.y, u0, by);
      float2 sc = sSCB2[k * 64 + lane];
      ax = fmaf(sc.x, u0, ax); ay = fmaf(sc.y, u0, ay);
      float u1 = rdlane(un, k);
      float2 dq = sD12Q[k * 64 + lane];
      ax = fmaf(dq.x, u1, ax); ay = fmaf(dq.y, u1, ay);
    }
    g_Q[((size_t)b * Tn + t) * 64 + lane] = make_float4(bx, by, ax, ay);
  }
}

// ---------------- Main: round-1 scan, VERBATIM (benched 4.87 ms, passing) ----
// 1 row/block, 8 waves, role-split, ONE barrier/step.
__global__ __launch_bounds__(512) void k_scan8() {
  __shared__ float2 sSAB[64 * 64];     // 32 KB
  __shared__ float  sSB2[64 * 64];     // 16 KB
  __shared__ float2 xbuf[2][8][64];    // 8 KB (parity double-buffered)
  __shared__ float2 abuf[2][8][64];    // 8 KB
  const float* ws = g_ws;
  const int tid = threadIdx.x, lane = tid & 63, w = tid >> 6;
  for (int i = tid; i < 4096; i += 512) sSAB[i] = ((const float2*)(ws + OFF_SAB))[i];
  for (int i = tid; i < 4096; i += 512) sSB2[i] = ws[OFF_SB2 + i];

  const bool isScan = (w < 4);
  float2 vA[32], vB[32];
  {
    const float2* P1 = (const float2*)(ws + (isScan ? OFF_PB : OFF_PF));
    const float2* P2 = (const float2*)(ws + (isScan ? OFF_PCB : OFF_PCF));
    const int jcol = (w & 3) * 32;
#pragma unroll
    for (int c = 0; c < 32; ++c) {
      vA[c] = P1[(jcol + c) * 64 + lane];
      vB[c] = P2[(jcol + c) * 64 + lane];
    }
  }
  const int b = blockIdx.x;
  float xl = ws[OFF_X0 + b * 128 + lane];
  float xh = ws[OFF_X0 + b * 128 + 64 + lane];
  float2 a2 = ((const float2*)(ws + OFF_A0))[b * 64 + lane];
  float accx = a2.x, accy = a2.y;
  const float4* Q = g_Q + (size_t)b * Tn * 64;
  float4 q = make_float4(0.f, 0.f, 0.f, 0.f);
  if (w == 4) q = Q[lane];
  size_t sbase = (size_t)b * Tn * 64 + lane;
  const int jb = __builtin_amdgcn_readfirstlane((w & 1) * 32);
  __syncthreads();

#pragma unroll 1
  for (int t = 0; t < Tn - 1; ++t) {
    const int p = t & 1;
    if (isScan) {
      // --- serial tanh scan (no in-chain capture; D11 strictly lower) ---
#pragma unroll
      for (int i = 0; i < 64; ++i) {
        float s = rdlane(accx, i);
        float e2 = __builtin_amdgcn_exp2f(s);
        float wi = fmaf(-2.f, __builtin_amdgcn_rcpf(1.f + e2), 1.f);
        float2 sp = sSAB[i * 64 + lane];
        accx = fmaf(sp.x, wi, accx);
        accy = fmaf(sp.y, wi, accy);
      }
      float ex = __builtin_amdgcn_exp2f(accx);               // accx now final
      float wx = fmaf(-2.f, __builtin_amdgcn_rcpf(1.f + ex), 1.f);
#pragma unroll
      for (int i = 0; i < 64; ++i) {
        float s = rdlane(accy, i);
        float e2 = __builtin_amdgcn_exp2f(s);
        float wi = fmaf(-2.f, __builtin_amdgcn_rcpf(1.f + e2), 1.f);
        accy = fmaf(sSB2[i * 64 + lane], wi, accy);
      }
      float ey = __builtin_amdgcn_exp2f(accy);               // accy now final
      float wy = fmaf(-2.f, __builtin_amdgcn_rcpf(1.f + ey), 1.f);
      if (w == 0) g_Ws[sbase + (size_t)t * 64] = make_float2(wx, wy);

      // --- w-contribution partials over this wave's 32 columns ---
      float px = 0.f, py = 0.f, pax = 0.f, pay = 0.f;
      float wsrc = (w < 2) ? wx : wy;
#pragma unroll
      for (int c = 0; c < 32; ++c) {
        float wj = rdlane(wsrc, jb + c);
        px  = fmaf(vA[c].x, wj, px);
        py  = fmaf(vA[c].y, wj, py);
        pax = fmaf(vB[c].x, wj, pax);
        pay = fmaf(vB[c].y, wj, pay);
      }
      xbuf[p][w][lane] = make_float2(px, py);
      abuf[p][w][lane] = make_float2(pax, pay);
      __syncthreads();                                       // the ONLY barrier
      float sax = 0.f, say = 0.f;
#pragma unroll
      for (int w2 = 0; w2 < 8; ++w2) {
        float2 av = abuf[p][w2][lane];
        sax += av.x; say += av.y;
      }
      accx = sax; accy = say;
    } else {
      // --- x-contribution partials (x(t) known before the scan) ---
      float4 qn = q;
      if (w == 4 && t + 1 < Tn - 1) qn = Q[(size_t)(t + 1) * 64 + lane];
      float px, py, pax, pay;
      if (w == 4) { px = q.x; py = q.y; pax = q.z; pay = q.w; }
      else        { px = 0.f; py = 0.f; pax = 0.f; pay = 0.f; }
      float xsrc = (w < 6) ? xl : xh;
#pragma unroll
      for (int c = 0; c < 32; ++c) {
        float xj = rdlane(xsrc, jb + c);
        px  = fmaf(vA[c].x, xj, px);
        py  = fmaf(vA[c].y, xj, py);
        pax = fmaf(vB[c].x, xj, pax);
        pay = fmaf(vB[c].y, xj, pay);
      }
      q = qn;
      xbuf[p][w][lane] = make_float2(px, py);
      abuf[p][w][lane] = make_float2(pax, pay);
      __syncthreads();                                       // the ONLY barrier
      float sxl = 0.f, sxh = 0.f;
#pragma unroll
      for (int w2 = 0; w2 < 8; ++w2) {
        float2 xv = xbuf[p][w2][lane];
        sxl += xv.x; sxh += xv.y;
      }
      xl = sxl; xh = sxh;
      if (w == 5) g_Xs[sbase + (size_t)(t + 1) * 64] = make_float2(xl, xh);
    }
  }
}

// ---------------- Output GEMM, BLOCKED (1 block/batch-row, LDS-staged
// matrices, coalesced Xs/Ws/u loads + readlane broadcast).
// FP values and fma order identical to the round-1 k_y -> bit-identical y.
__global__ __launch_bounds__(512) void k_y2(const void* __restrict__ x0s,
                                            const void* __restrict__ u_in,
                                            void* __restrict__ out) {
  __shared__ float sC2Y[4096], sD21Y[4096], sD22Y[1024];    // 36 KB
  const float* ws = g_ws;
  const int f = g_isf32;
  const int tid = threadIdx.x, lane = tid & 63, w = tid >> 6;
  for (int i = tid; i < 4096; i += 512) { sC2Y[i] = ws[OFF_C2Y + i]; sD21Y[i] = ws[OFF_D21Y + i]; }
  for (int i = tid; i < 1024; i += 512) sD22Y[i] = ws[OFF_D22Y + i];
  __syncthreads();
  const int b = blockIdx.x;
  const int o = lane & 31, h = lane >> 5;
  for (int t = w; t < Tn; t += 8) {
    if (t == 0) {
      if (lane < 32) {
        size_t oi = (size_t)b * Tn * 32 + o;
        float v = ld(x0s, b * 32 + o, f);
        if (f) ((float*)out)[oi] = v;
        else   ((__hip_bfloat16*)out)[oi] = __float2bfloat16(v);
      }
      continue;
    }
    float2 xv2 = g_Xs[((size_t)b * Tn + t) * 64 + lane];      // (xl, xh)
    float2 wv  = g_Ws[((size_t)b * Tn + t - 1) * 64 + lane];  // (wx, wy)
    float uy = 0.f;
    if (lane < 32) uy = ld(u_in, ((size_t)b * Tn + t - 1) * 32 + lane, f);
    float acc = 0.f;
#pragma unroll 8
    for (int l = 0; l < 64; ++l) {
      float xle = rdlane(xv2.x, l), xhe = rdlane(xv2.y, l);
      float xvv = h ? xhe : xle;
      acc = fmaf(xvv, sC2Y[(l + 64 * h) * 32 + o], acc);
    }
#pragma unroll 8
    for (int l = 0; l < 64; ++l) {
      float wxe = rdlane(wv.x, l), wye = rdlane(wv.y, l);
      float wvv = h ? wye : wxe;
      acc = fmaf(wvv, sD21Y[(l + 64 * h) * 32 + o], acc);
    }
    if (h == 0) {
#pragma unroll 8
      for (int k = 0; k < 32; ++k)
        acc = fmaf(rdlane(uy, k), sD22Y[k * 32 + o], acc);
    }
    acc += __shfl_down(acc, 32);
    if (lane < 32) {
      size_t oi = ((size_t)b * Tn + t) * 32 + o;
      if (f) ((float*)out)[oi] = acc;
      else   ((__hip_bfloat16*)out)[oi] = __float2bfloat16(acc);
    }
  }
}

extern "C" void kernel_launch(void* const* d_in, const int* in_sizes, int n_in,
                              void* d_out, int out_size, void* d_ws, size_t ws_size,
                              hipStream_t stream) {
  const void* x0s = d_in[0];
  const void* u   = d_in[1];
  const void* X   = d_in[2];
  const void* Y   = d_in[3];
  const void* B2  = d_in[4];
  const void* C2  = d_in[5];
  const void* D21 = d_in[6];
  const void* D22 = d_in[7];
  const void* D12 = d_in[8];
  (void)d_ws; (void)ws_size; (void)in_sizes; (void)n_in; (void)out_size;

  hipLaunchKernelGGL(k_detect,  dim3(1),     dim3(64),   0, stream, X);
  hipLaunchKernelGGL(k_H,       dim3(576),   dim3(256),  0, stream, X);
  hipLaunchKernelGGL(k_derived, dim3(69),    dim3(256),  0, stream, Y, C2);

  hipError_t e = hipFuncSetAttribute((const void*)k_inv_lds,
                                     hipFuncAttributeMaxDynamicSharedMemorySize,
                                     139264);
  if (e == hipSuccess) {
    hipLaunchKernelGGL(k_inv_lds, dim3(1), dim3(1024), 139264, stream);
  } else {
    (void)hipGetLastError();
    hipLaunchKernelGGL(k_inv,     dim3(1), dim3(1024), 0, stream);
  }

  hipLaunchKernelGGL(k_fuse,    dim3(160),   dim3(256),  0, stream, B2, C2);
  hipLaunchKernelGGL(k_w2,      dim3(16),    dim3(256),  0, stream);
  hipLaunchKernelGGL(k_cf,      dim3(144),   dim3(256),  0, stream);
  hipLaunchKernelGGL(k_pk,      dim3(228),   dim3(256),  0, stream, D12, C2, D21, D22);
  hipLaunchKernelGGL(k_x0a0,    dim3(192),   dim3(256),  0, stream, x0s, u);
  hipLaunchKernelGGL(k_q2,      dim3(256),   dim3(512),  0, stream, u);
  hipLaunchKernelGGL(k_scan8,   dim3(256),   dim3(512),  0, stream);
  hipLaunchKernelGGL(k_y2,      dim3(256),   dim3(512),  0, stream, x0s, u, d_out);
}